// Round 11
// baseline (140.613 us; speedup 1.0000x reference)
//
#include <hip/hip_runtime.h>
#include <hip/hip_bf16.h>
#include <stdint.h>

#define BB    2
#define NRES  2048
#define TOPK  30
#define NRBF  16
#define NFEAT 416
#define NCH   128
#define NSTR  212          // feat row stride in u32: 848B, 16B-aligned; 212%32=20 -> <=2-way (free)
#define NKT   13           // k-steps of 32

typedef __attribute__((ext_vector_type(8))) short bf16x8;
typedef __attribute__((ext_vector_type(4))) float f32x4;
typedef unsigned long long u64;

// atoms record order: 0=N,1=Ca,2=Cb,3=C,4=O  (matches reference stack order)
__constant__ int c_pa[24] = {0,1,2,3,3,3,0,0,2,0,1,2,1,2,1,4,3,4,0,4,2,4,4,1};
__constant__ int c_pb[24] = {0,1,2,0,1,2,1,2,1,3,3,3,0,0,2,4,4,3,4,0,4,1,2,4};

static __device__ __forceinline__ unsigned short f2bf(float x) {
  __hip_bfloat16 h = __float2bfloat16(x);
  return *reinterpret_cast<unsigned short*>(&h);
}
static __device__ __forceinline__ unsigned pack2(float lo, float hi) {
  return (unsigned)f2bf(lo) | ((unsigned)f2bf(hi) << 16);
}
static __device__ __forceinline__ u64 umin64(u64 a, u64 b) { return a < b ? a : b; }
static __device__ __forceinline__ u64 umax64(u64 a, u64 b) { return a > b ? a : b; }

// ---------------- kernel 1: prep = atoms records + Cpk + wB (merged launch) ----------
__global__ __launch_bounds__(256) void prep_kernel(const float* __restrict__ X,
                                                   const float* __restrict__ w_edge,
                                                   float* __restrict__ atoms,
                                                   float4* __restrict__ Cpk,
                                                   unsigned short* __restrict__ wB) {
  if (blockIdx.x < 16) {
    int id = blockIdx.x * 256 + threadIdx.x;
    const float* x = X + (size_t)id * 12;
    float nx = x[0], ny = x[1], nz = x[2];
    float cx = x[3], cy = x[4], cz = x[5];
    float ax = x[6], ay = x[7], az = x[8];
    float ox = x[9], oy = x[10], oz = x[11];
    float bx = ax - nx, by = ay - ny, bz = az - nz;
    float ccx = cx - ax, ccy = cy - ay, ccz = cz - az;
    float crx = by * ccz - bz * ccy;
    float cry = bz * ccx - bx * ccz;
    float crz = bx * ccy - by * ccx;
    float cbx = -0.58273431f * crx + 0.56802827f * bx - 0.54067466f * ccx + ax;
    float cby = -0.58273431f * cry + 0.56802827f * by - 0.54067466f * ccy + ay;
    float cbz = -0.58273431f * crz + 0.56802827f * bz - 0.54067466f * ccz + az;
    float* r = atoms + (size_t)id * 16;
    r[0] = nx;  r[1] = ny;  r[2] = nz;
    r[3] = ax;  r[4] = ay;  r[5] = az;
    r[6] = cbx; r[7] = cby; r[8] = cbz;
    r[9] = cx;  r[10] = cy; r[11] = cz;
    r[12] = ox; r[13] = oy; r[14] = oz;
    r[15] = 0.f;
    Cpk[id] = make_float4(cx, cy, cz, 0.f);
  } else {
    // wB[((kt*8+nt)*64+lane)*8+j] = bf16(w_edge[(kt*32+(lane>>4)*8+j)*128 + nt*16+(lane&15)])
    int id = (blockIdx.x - 16) * 256 + threadIdx.x;
    if (id >= NFEAT * NCH) return;
    int j    = id & 7;
    int lane = (id >> 3) & 63;
    int nt   = (id >> 9) & 7;
    int kt   = id >> 12;
    int col  = nt * 16 + (lane & 15);
    int k    = kt * 32 + ((lane >> 4) << 3) + j;
    wB[id] = f2bf(w_edge[(size_t)k * NCH + col]);
  }
}

// ---------------- kernel 2 (FUSED): topk (wave 0) + features + MFMA + LayerNorm -------
// One residue per block, 256 threads = 4 waves.
// Phase T: wave 0 runs the 32-key/lane register tournament (2 winners/butterfly),
//          writes eidx/dn to LDS and E_idx to global. Other blocks' waves hide this.
// Phases A-E: identical structure to the proven round-7 kernel.
__global__ __launch_bounds__(256) void fused_kernel(
    const float* __restrict__ atoms, const float4* __restrict__ Cpk,
    const int* __restrict__ ridx, const int* __restrict__ chain,
    const float* __restrict__ w_pos, const float* __restrict__ b_pos,
    const unsigned short* __restrict__ wB,
    const float* __restrict__ gamma, const float* __restrict__ beta,
    float* __restrict__ outE, float* __restrict__ outI) {
  __shared__ __align__(16) unsigned feat[32][NSTR];   // 27.1 KB bf16x2-packed features
  __shared__ float nat[TOPK][16];
  __shared__ float iat[16];
  __shared__ float dn_s[TOPK];
  __shared__ int   eidx_s[TOPK];
  __shared__ int   dsel[TOPK];
  __shared__ float2 lnp[32][4];              // per-row (sum,sumsq) per n-quarter

  int tid = threadIdx.x;
  int bi = blockIdx.x;                        // one residue per block
  int b = bi >> 11;
  int nq = tid >> 6, lane = tid & 63;
  int q = lane >> 4, ccol = lane & 15;

  // ---- phase T: tournament on wave 0; waves 1-3 zero-pad feat rows 30,31 ----
  if (nq == 0) {
    const float4* Cb = Cpk + (size_t)b * NRES;
    float4 ci = Cb[bi & (NRES - 1)];
    u64 key[4][8];
    u64 g1[4], g2[4];
#pragma unroll
    for (int g = 0; g < 4; ++g) {
      g1[g] = ~0ull; g2[g] = ~0ull;
#pragma unroll
      for (int s = 0; s < 8; ++s) {
        int j = lane + 64 * (g * 8 + s);
        float4 cj = Cb[j];
        float dx = cj.x - ci.x, dy = cj.y - ci.y, dz = cj.z - ci.z;
        // match numpy op-for-op: ((dx*dx + dy*dy) + dz*dz) + 1e-6, no fma contraction
        float sm = __fadd_rn(__fadd_rn(__fadd_rn(__fmul_rn(dx, dx), __fmul_rn(dy, dy)),
                                       __fmul_rn(dz, dz)), 1e-6f);
        float d = sqrtf(sm);
        u64 kk = ((u64)__float_as_uint(d) << 32) | (unsigned)j;  // unique keys
        key[g][s] = kk;
        if (kk < g1[g]) { g2[g] = g1[g]; g1[g] = kk; }
        else if (kk < g2[g]) g2[g] = kk;
      }
    }
    for (int kk2 = 0; kk2 < TOPK / 2; ++kk2) {
      u64 x1 = umin64(g1[0], g1[1]);
      u64 x2 = umin64(umax64(g1[0], g1[1]), umin64(g2[0], g2[1]));
      u64 y1 = umin64(g1[2], g1[3]);
      u64 y2 = umin64(umax64(g1[2], g1[3]), umin64(g2[2], g2[3]));
      u64 m1 = umin64(x1, y1);
      u64 m2 = umin64(umax64(x1, y1), umin64(x2, y2));
#pragma unroll
      for (int off = 32; off; off >>= 1) {
        u64 o1 = __shfl_xor(m1, off, 64);
        u64 o2 = __shfl_xor(m2, off, 64);
        u64 n1 = umin64(m1, o1);
        u64 n2 = umin64(umax64(m1, o1), umin64(m2, o2));
        m1 = n1; m2 = n2;
      }
      if (lane == 0) {
        int i1 = (int)(unsigned)m1, i2 = (int)(unsigned)m2;
        int o = 2 * kk2;
        eidx_s[o] = i1;         eidx_s[o + 1] = i2;
        dn_s[o]   = __uint_as_float((unsigned)(m1 >> 32));
        dn_s[o+1] = __uint_as_float((unsigned)(m2 >> 32));
        outI[(size_t)bi * TOPK + o]     = (float)i1;   // E_idx as FLOAT32
        outI[(size_t)bi * TOPK + o + 1] = (float)i2;
      }
#pragma unroll
      for (int g = 0; g < 4; ++g) {
        bool hit = (g1[g] == m1) | (g1[g] == m2) | (g2[g] == m2);
        if (hit) {
          u64 n1 = ~0ull, n2 = ~0ull;
#pragma unroll
          for (int s = 0; s < 8; ++s) {
            u64 kv = key[g][s];
            if (kv == m1 || kv == m2) { kv = ~0ull; key[g][s] = kv; }
            if (kv < n1) { n2 = n1; n1 = kv; }
            else if (kv < n2) n2 = kv;
          }
          g1[g] = n1; g2[g] = n2;
        }
      }
    }
  } else {
    for (int idx = tid - 64; idx < 2 * NSTR; idx += 192)
      feat[30 + idx / NSTR][idx % NSTR] = 0u;   // zero pad rows 30,31
  }
  __syncthreads();

  // ---- phase A/B: pos bucket + own atoms + neighbor gather (from LDS eidx) ----
  if (tid < TOPK) {
    int j = eidx_s[tid];
    int off = ridx[bi] - ridx[b * NRES + j];
    int ec = (chain[bi] == chain[b * NRES + j]) ? 1 : 0;
    int d = off + 32; d = d < 0 ? 0 : (d > 64 ? 64 : d);
    dsel[tid] = ec ? d : 65;
  }
  if (tid >= 64 && tid < 80) iat[tid - 64] = atoms[(size_t)bi * 16 + (tid - 64)];
  for (int idx = tid; idx < TOPK * 16; idx += 256) {
    int e = idx >> 4, f = idx & 15;
    nat[e][f] = atoms[((size_t)(b * NRES) + eidx_s[e]) * 16 + f];
  }
  __syncthreads();

  // ---- phase C: features (bf16x2 packed) ----
  if (tid < TOPK * 8) {                       // pos: 30 edges x 8 u32 pairs
    int e = tid >> 3, p = tid & 7;
    int f0 = p * 2, ds = dsel[e];
    float v0 = w_pos[ds * 16 + f0] + b_pos[f0];
    float v1 = w_pos[ds * 16 + f0 + 1] + b_pos[f0 + 1];
    feat[e][p] = pack2(v0, v1);
  }
  for (int idx = tid; idx < TOPK * 25; idx += 256) {   // RBF: 30 edges x 25 groups
    int e = idx / 25, g = idx - e * 25;
    float d;
    if (g == 0) {
      d = dn_s[e];
    } else {
      int qq = g - 1;
      const float* A  = &iat[c_pa[qq] * 3];
      const float* Bv = &nat[e][c_pb[qq] * 3];
      float dx = A[0] - Bv[0], dy = A[1] - Bv[1], dz = A[2] - Bv[2];
      d = sqrtf(dx * dx + dy * dy + dz * dz + 1e-6f);
    }
    unsigned tmp[8];
#pragma unroll
    for (int j = 0; j < 8; ++j) {
      float mu0 = 2.0f + (float)(2 * j) * (20.0f / 15.0f);
      float mu1 = 2.0f + (float)(2 * j + 1) * (20.0f / 15.0f);
      float t0 = (d - mu0) * 0.8f, t1 = (d - mu1) * 0.8f;
      tmp[j] = pack2(__expf(-t0 * t0), __expf(-t1 * t1));
    }
    unsigned* dst = &feat[e][8 + 8 * g];      // (8+8g)*4 bytes: 16B-aligned
    *(uint4*)(dst)     = make_uint4(tmp[0], tmp[1], tmp[2], tmp[3]);
    *(uint4*)(dst + 4) = make_uint4(tmp[4], tmp[5], tmp[6], tmp[7]);
  }
  __syncthreads();

  // ---- phase D: MFMA 16x16x32 bf16 (round-7 structure, in-loop B loads) ----
  const uint4* arow0 = (const uint4*)&feat[ccol][0];       // m-half 0: rows 0..15
  const uint4* arow1 = (const uint4*)&feat[16 + ccol][0];  // m-half 1: rows 16..31
  const bf16x8* wBv = (const bf16x8*)wB;

  f32x4 acc00 = {}, acc01 = {}, acc10 = {}, acc11 = {};    // [mhalf][jn]
#pragma unroll
  for (int kt = 0; kt < NKT; ++kt) {
    union { uint4 u4; bf16x8 v; } a0, a1;
    a0.u4 = arow0[kt * 4 + q];                // ds_read_b128
    a1.u4 = arow1[kt * 4 + q];
    bf16x8 b0 = wBv[(size_t)(kt * 8 + nq * 2 + 0) * 64 + lane];  // 1KB contiguous
    bf16x8 b1 = wBv[(size_t)(kt * 8 + nq * 2 + 1) * 64 + lane];
    acc00 = __builtin_amdgcn_mfma_f32_16x16x32_bf16(a0.v, b0, acc00, 0, 0, 0);
    acc01 = __builtin_amdgcn_mfma_f32_16x16x32_bf16(a0.v, b1, acc01, 0, 0, 0);
    acc10 = __builtin_amdgcn_mfma_f32_16x16x32_bf16(a1.v, b0, acc10, 0, 0, 0);
    acc11 = __builtin_amdgcn_mfma_f32_16x16x32_bf16(a1.v, b1, acc11, 0, 0, 0);
  }

  // ---- phase E: LayerNorm partials + store ----
#pragma unroll
  for (int mh = 0; mh < 2; ++mh) {
#pragma unroll
    for (int reg = 0; reg < 4; ++reg) {
      float v0 = mh ? acc10[reg] : acc00[reg];
      float v1 = mh ? acc11[reg] : acc01[reg];
      float s = v0 + v1, ss = v0 * v0 + v1 * v1;
      s  += __shfl_xor(s, 1, 64);  ss += __shfl_xor(ss, 1, 64);
      s  += __shfl_xor(s, 2, 64);  ss += __shfl_xor(ss, 2, 64);
      s  += __shfl_xor(s, 4, 64);  ss += __shfl_xor(ss, 4, 64);
      s  += __shfl_xor(s, 8, 64);  ss += __shfl_xor(ss, 8, 64);
      if (ccol == 0) lnp[(mh << 4) + q * 4 + reg][nq] = make_float2(s, ss);
    }
  }
  __syncthreads();

  float g0 = gamma[(nq * 2 + 0) * 16 + ccol], be0 = beta[(nq * 2 + 0) * 16 + ccol];
  float g1 = gamma[(nq * 2 + 1) * 16 + ccol], be1 = beta[(nq * 2 + 1) * 16 + ccol];
#pragma unroll
  for (int mh = 0; mh < 2; ++mh) {
#pragma unroll
    for (int reg = 0; reg < 4; ++reg) {
      int m = (mh << 4) + q * 4 + reg;
      if (m < TOPK) {
        float2 p0 = lnp[m][0], p1 = lnp[m][1], p2 = lnp[m][2], p3 = lnp[m][3];
        float s = (p0.x + p1.x) + (p2.x + p3.x);
        float ss = (p0.y + p1.y) + (p2.y + p3.y);
        float mu = s * (1.0f / 128.0f);
        float var = ss * (1.0f / 128.0f) - mu * mu;
        float rstd = rsqrtf(var + 1e-5f);
        float va = mh ? acc10[reg] : acc00[reg];
        float vb = mh ? acc11[reg] : acc01[reg];
        float* o = outE + ((size_t)bi * TOPK + m) * NCH + ccol;
        o[(nq * 2 + 0) * 16] = (va - mu) * rstd * g0 + be0;
        o[(nq * 2 + 1) * 16] = (vb - mu) * rstd * g1 + be1;
      }
    }
  }
}

extern "C" void kernel_launch(void* const* d_in, const int* in_sizes, int n_in,
                              void* d_out, int out_size, void* d_ws, size_t ws_size,
                              hipStream_t stream) {
  const float* X      = (const float*)d_in[0];
  const int*   ridx   = (const int*)d_in[2];
  const int*   chain  = (const int*)d_in[3];
  const float* w_pos  = (const float*)d_in[4];
  const float* b_pos  = (const float*)d_in[5];
  const float* w_edge = (const float*)d_in[6];
  const float* gamma  = (const float*)d_in[7];
  const float* beta   = (const float*)d_in[8];

  float* outE = (float*)d_out;                         // output 0: E, float32
  float* outI = outE + (size_t)BB * NRES * TOPK * NCH; // output 1: E_idx as float32

  // workspace layout
  char* p = (char*)d_ws;
  float* atoms = (float*)p;                 p += (size_t)BB * NRES * 16 * 4;   // 256 KB
  unsigned short* wB = (unsigned short*)p;  p += (size_t)NCH * NFEAT * 2;      // 104 KB
  float4* Cpk  = (float4*)p;                // 64 KB

  prep_kernel<<<16 + (NFEAT * NCH) / 256, 256, 0, stream>>>(X, w_edge, atoms, Cpk, wB);
  fused_kernel<<<BB * NRES, 256, 0, stream>>>(atoms, Cpk, ridx, chain,
                                              w_pos, b_pos, wB, gamma, beta, outE, outI);
}

// Round 12
// 77.382 us; speedup vs baseline: 1.8171x; 1.8171x over previous
//
#include <hip/hip_runtime.h>
#include <hip/hip_bf16.h>
#include <stdint.h>

#define BB    2
#define NRES  2048
#define TOPK  30
#define NRBF  16
#define NFEAT 416
#define NCH   128
#define NS8   108          // feat row stride in u32 (fp8): 432B = 16B-aligned; 12*ccol mod 32 -> 2-way (free)
#define NKT   13           // k-steps of 32

typedef __attribute__((ext_vector_type(4))) float f32x4;
typedef unsigned long long u64;

// atoms record order: 0=N,1=Ca,2=Cb,3=C,4=O  (matches reference stack order)
__constant__ int c_pa[24] = {0,1,2,3,3,3,0,0,2,0,1,2,1,2,1,4,3,4,0,4,2,4,4,1};
__constant__ int c_pb[24] = {0,1,2,0,1,2,1,2,1,3,3,3,0,0,2,4,4,3,4,0,4,1,2,4};

static __device__ __forceinline__ unsigned pack4_fp8(float f0, float f1, float f2, float f3) {
  unsigned r = 0;
  r = __builtin_amdgcn_cvt_pk_fp8_f32(f0, f1, r, false);  // bytes 0,1
  r = __builtin_amdgcn_cvt_pk_fp8_f32(f2, f3, r, true);   // bytes 2,3
  return r;
}

// ---------------- kernel 1: prep = atoms records + Cpk + wB-fp8 (merged launch) -------
// blocks 0..15: atoms+Cpk. blocks 16..67: wB8 fragment-major fp8 transpose:
// byte wB8[((kt*8+nt)*64+lane)*8+j] = fp8(w_edge[(kt*32+(lane>>4)*8+j)*128 + nt*16+(lane&15)])
__global__ __launch_bounds__(256) void prep_kernel(const float* __restrict__ X,
                                                   const float* __restrict__ w_edge,
                                                   float* __restrict__ atoms,
                                                   float4* __restrict__ Cpk,
                                                   unsigned* __restrict__ wB8) {
  if (blockIdx.x < 16) {
    int id = blockIdx.x * 256 + threadIdx.x;
    const float* x = X + (size_t)id * 12;
    float nx = x[0], ny = x[1], nz = x[2];
    float cx = x[3], cy = x[4], cz = x[5];
    float ax = x[6], ay = x[7], az = x[8];
    float ox = x[9], oy = x[10], oz = x[11];
    float bx = ax - nx, by = ay - ny, bz = az - nz;
    float ccx = cx - ax, ccy = cy - ay, ccz = cz - az;
    float crx = by * ccz - bz * ccy;
    float cry = bz * ccx - bx * ccz;
    float crz = bx * ccy - by * ccx;
    float cbx = -0.58273431f * crx + 0.56802827f * bx - 0.54067466f * ccx + ax;
    float cby = -0.58273431f * cry + 0.56802827f * by - 0.54067466f * ccy + ay;
    float cbz = -0.58273431f * crz + 0.56802827f * bz - 0.54067466f * ccz + az;
    float* r = atoms + (size_t)id * 16;
    r[0] = nx;  r[1] = ny;  r[2] = nz;
    r[3] = ax;  r[4] = ay;  r[5] = az;
    r[6] = cbx; r[7] = cby; r[8] = cbz;
    r[9] = cx;  r[10] = cy; r[11] = cz;
    r[12] = ox; r[13] = oy; r[14] = oz;
    r[15] = 0.f;
    Cpk[id] = make_float4(cx, cy, cz, 0.f);
  } else {
    int id = (blockIdx.x - 16) * 256 + threadIdx.x;  // u32 index
    if (id >= NFEAT * NCH / 4) return;
    int bb   = id * 4;
    int j0   = bb & 7;
    int lane = (bb >> 3) & 63;
    int nt   = (bb >> 9) & 7;
    int kt   = bb >> 12;
    int col  = nt * 16 + (lane & 15);
    int kb   = kt * 32 + ((lane >> 4) << 3) + j0;
    float f0 = w_edge[(size_t)(kb + 0) * NCH + col];
    float f1 = w_edge[(size_t)(kb + 1) * NCH + col];
    float f2 = w_edge[(size_t)(kb + 2) * NCH + col];
    float f3 = w_edge[(size_t)(kb + 3) * NCH + col];
    wB8[id] = pack4_fp8(f0, f1, f2, f3);
  }
}

// ---------------- kernel 2: top-30, ONE WAVE per residue, sub-grouped tournament ------
// (exact round-7 version: best measured)
__global__ __launch_bounds__(256) void topk_kernel(const float4* __restrict__ Cpk,
                                                   int* __restrict__ eidx,
                                                   float* __restrict__ dn,
                                                   float* __restrict__ outI) {
  int tid = threadIdx.x;
  int lane = tid & 63;
  int bi = blockIdx.x * 4 + (tid >> 6);
  int b = bi >> 11;
  int i = bi & (NRES - 1);
  const float4* Cb = Cpk + (size_t)b * NRES;
  float4 ci = Cb[i];

  u64 key[4][8];
  u64 sub[4];
#pragma unroll
  for (int g = 0; g < 4; ++g) {
    sub[g] = ~0ull;
#pragma unroll
    for (int s = 0; s < 8; ++s) {
      int j = lane + 64 * (g * 8 + s);
      float4 cj = Cb[j];
      float dx = cj.x - ci.x, dy = cj.y - ci.y, dz = cj.z - ci.z;
      // match numpy op-for-op: ((dx*dx + dy*dy) + dz*dz) + 1e-6, no fma contraction
      float sm = __fadd_rn(__fadd_rn(__fadd_rn(__fmul_rn(dx, dx), __fmul_rn(dy, dy)),
                                     __fmul_rn(dz, dz)), 1e-6f);
      float d = sqrtf(sm);
      key[g][s] = ((u64)__float_as_uint(d) << 32) | (unsigned)j;
      if (key[g][s] < sub[g]) sub[g] = key[g][s];
    }
  }

  for (int k = 0; k < TOPK; ++k) {
    u64 m01 = sub[0] < sub[1] ? sub[0] : sub[1];
    u64 m23 = sub[2] < sub[3] ? sub[2] : sub[3];
    u64 gm = m01 < m23 ? m01 : m23;
#pragma unroll
    for (int off = 32; off; off >>= 1) {          // butterfly: all lanes get wave min
      u64 o = __shfl_xor(gm, off, 64);
      if (o < gm) gm = o;
    }
    if (lane == 0) {
      int idx = (int)(unsigned)(gm & 0xffffffffu);
      eidx[(size_t)bi * TOPK + k] = idx;
      dn[(size_t)bi * TOPK + k] = __uint_as_float((unsigned)(gm >> 32));
      outI[(size_t)bi * TOPK + k] = (float)idx;   // d_out is FLOAT32
    }
#pragma unroll
    for (int g = 0; g < 4; ++g) {                 // owner subgroup: invalidate + re-min 8
      if (sub[g] == gm) {
        sub[g] = ~0ull;
#pragma unroll
        for (int s = 0; s < 8; ++s) {
          if (key[g][s] == gm) key[g][s] = ~0ull;
          if (key[g][s] < sub[g]) sub[g] = key[g][s];
        }
      }
    }
  }
}

// ---------------- kernel 3: features (fp8) + MFMA fp8 GEMM + LayerNorm ----------------
// 256 threads = 4 waves; wave nq -> n-tiles {2nq,2nq+1}, both m-halves. Round-7 structure.
__global__ __launch_bounds__(256) void edge_mfma_kernel(
    const float* __restrict__ atoms, const int* __restrict__ eidx_g,
    const float* __restrict__ dn_g, const int* __restrict__ ridx,
    const int* __restrict__ chain, const float* __restrict__ w_pos,
    const float* __restrict__ b_pos, const unsigned* __restrict__ wB8,
    const float* __restrict__ gamma, const float* __restrict__ beta,
    float* __restrict__ outE) {
  __shared__ __align__(16) unsigned feat8[32 * NS8];  // 13.8 KB fp8x4-packed features
  __shared__ float nat[TOPK][16];
  __shared__ float iat[16];
  __shared__ float dn_s[TOPK];
  __shared__ int   dsel[TOPK];
  __shared__ float2 lnp[32][4];              // per-row (sum,sumsq) per n-quarter

  int tid = threadIdx.x;
  int bi = blockIdx.x;                        // one residue per block
  int b = bi >> 11;
  int nq = tid >> 6, lane = tid & 63;
  int q = lane >> 4, ccol = lane & 15;

  // ---- phase A/B: edge list + pos bucket + own atoms + neighbor gather + zero-pad ----
  if (tid < TOPK) {
    dn_s[tid] = dn_g[(size_t)bi * TOPK + tid];
    int j = eidx_g[(size_t)bi * TOPK + tid];
    int off = ridx[bi] - ridx[b * NRES + j];
    int ec = (chain[bi] == chain[b * NRES + j]) ? 1 : 0;
    int d = off + 32; d = d < 0 ? 0 : (d > 64 ? 64 : d);
    dsel[tid] = ec ? d : 65;
  }
  if (tid >= 64 && tid < 80) iat[tid - 64] = atoms[(size_t)bi * 16 + (tid - 64)];
  for (int idx = tid; idx < TOPK * 16; idx += 256) {
    int e = idx >> 4, f = idx & 15;
    nat[e][f] = atoms[((size_t)(b * NRES) + eidx_g[(size_t)bi * TOPK + e]) * 16 + f];
  }
  for (int idx = tid; idx < 2 * NS8; idx += 256)
    feat8[30 * NS8 + idx] = 0u;               // zero pad rows 30,31
  __syncthreads();

  // ---- phase C: features (fp8x4 packed) ----
  if (tid < TOPK * 4) {                       // pos: 30 edges x 4 u32 (16 fp8)
    int e = tid >> 2, p = tid & 3;
    int f0 = p * 4, ds = dsel[e];
    feat8[e * NS8 + p] = pack4_fp8(w_pos[ds * 16 + f0 + 0] + b_pos[f0 + 0],
                                   w_pos[ds * 16 + f0 + 1] + b_pos[f0 + 1],
                                   w_pos[ds * 16 + f0 + 2] + b_pos[f0 + 2],
                                   w_pos[ds * 16 + f0 + 3] + b_pos[f0 + 3]);
  }
  for (int idx = tid; idx < TOPK * 25; idx += 256) {   // RBF: 30 edges x 25 groups
    int e = idx / 25, g = idx - e * 25;
    float d;
    if (g == 0) {
      d = dn_s[e];
    } else {
      int qq = g - 1;
      const float* A  = &iat[c_pa[qq] * 3];
      const float* Bv = &nat[e][c_pb[qq] * 3];
      float dx = A[0] - Bv[0], dy = A[1] - Bv[1], dz = A[2] - Bv[2];
      d = sqrtf(dx * dx + dy * dy + dz * dz + 1e-6f);
    }
    float v[16];
#pragma unroll
    for (int j = 0; j < 16; ++j) {
      float mu = 2.0f + (float)j * (20.0f / 15.0f);  // linspace(2,22,16)
      float t = (d - mu) * 0.8f;                     // sigma = 1.25
      v[j] = __expf(-t * t);
    }
    // group g occupies u32 slots 4+4g..7+4g; byte offset 16+16g within 432B row: 16B-aligned
    uint4 w4 = make_uint4(pack4_fp8(v[0], v[1], v[2], v[3]),
                          pack4_fp8(v[4], v[5], v[6], v[7]),
                          pack4_fp8(v[8], v[9], v[10], v[11]),
                          pack4_fp8(v[12], v[13], v[14], v[15]));
    *(uint4*)&feat8[e * NS8 + 4 + 4 * g] = w4;
  }
  __syncthreads();

  // ---- phase D: MFMA 16x16x32 fp8_fp8; A frag = ds_read_b64, B frag = 8B global ----
  const unsigned* ar0 = &feat8[ccol * NS8];          // m-half 0: rows 0..15
  const unsigned* ar1 = &feat8[(16 + ccol) * NS8];   // m-half 1: rows 16..31
  const u64* wBll = (const u64*)wB8;

  f32x4 acc00 = {}, acc01 = {}, acc10 = {}, acc11 = {};    // [mhalf][jn]
#pragma unroll
  for (int kt = 0; kt < NKT; ++kt) {
    union { unsigned u[2]; long long l; } a0, a1;
    int ao = kt * 8 + q * 2;
    a0.u[0] = ar0[ao]; a0.u[1] = ar0[ao + 1];        // ds_read_b64
    a1.u[0] = ar1[ao]; a1.u[1] = ar1[ao + 1];
    long long b0 = (long long)wBll[(size_t)(kt * 8 + nq * 2 + 0) * 64 + lane];  // 512B/inst
    long long b1 = (long long)wBll[(size_t)(kt * 8 + nq * 2 + 1) * 64 + lane];
    acc00 = __builtin_amdgcn_mfma_f32_16x16x32_fp8_fp8(a0.l, b0, acc00, 0, 0, 0);
    acc01 = __builtin_amdgcn_mfma_f32_16x16x32_fp8_fp8(a0.l, b1, acc01, 0, 0, 0);
    acc10 = __builtin_amdgcn_mfma_f32_16x16x32_fp8_fp8(a1.l, b0, acc10, 0, 0, 0);
    acc11 = __builtin_amdgcn_mfma_f32_16x16x32_fp8_fp8(a1.l, b1, acc11, 0, 0, 0);
  }

  // ---- phase E: LayerNorm partials + store ----
#pragma unroll
  for (int mh = 0; mh < 2; ++mh) {
#pragma unroll
    for (int reg = 0; reg < 4; ++reg) {
      float v0 = mh ? acc10[reg] : acc00[reg];
      float v1 = mh ? acc11[reg] : acc01[reg];
      float s = v0 + v1, ss = v0 * v0 + v1 * v1;
      s  += __shfl_xor(s, 1, 64);  ss += __shfl_xor(ss, 1, 64);
      s  += __shfl_xor(s, 2, 64);  ss += __shfl_xor(ss, 2, 64);
      s  += __shfl_xor(s, 4, 64);  ss += __shfl_xor(ss, 4, 64);
      s  += __shfl_xor(s, 8, 64);  ss += __shfl_xor(ss, 8, 64);
      if (ccol == 0) lnp[(mh << 4) + q * 4 + reg][nq] = make_float2(s, ss);
    }
  }
  __syncthreads();

  float g0 = gamma[(nq * 2 + 0) * 16 + ccol], be0 = beta[(nq * 2 + 0) * 16 + ccol];
  float g1 = gamma[(nq * 2 + 1) * 16 + ccol], be1 = beta[(nq * 2 + 1) * 16 + ccol];
#pragma unroll
  for (int mh = 0; mh < 2; ++mh) {
#pragma unroll
    for (int reg = 0; reg < 4; ++reg) {
      int m = (mh << 4) + q * 4 + reg;
      if (m < TOPK) {
        float2 p0 = lnp[m][0], p1 = lnp[m][1], p2 = lnp[m][2], p3 = lnp[m][3];
        float s = (p0.x + p1.x) + (p2.x + p3.x);
        float ss = (p0.y + p1.y) + (p2.y + p3.y);
        float mu = s * (1.0f / 128.0f);
        float var = ss * (1.0f / 128.0f) - mu * mu;
        float rstd = rsqrtf(var + 1e-5f);
        float va = mh ? acc10[reg] : acc00[reg];
        float vb = mh ? acc11[reg] : acc01[reg];
        float* o = outE + ((size_t)bi * TOPK + m) * NCH + ccol;
        o[(nq * 2 + 0) * 16] = (va - mu) * rstd * g0 + be0;
        o[(nq * 2 + 1) * 16] = (vb - mu) * rstd * g1 + be1;
      }
    }
  }
}

extern "C" void kernel_launch(void* const* d_in, const int* in_sizes, int n_in,
                              void* d_out, int out_size, void* d_ws, size_t ws_size,
                              hipStream_t stream) {
  const float* X      = (const float*)d_in[0];
  const int*   ridx   = (const int*)d_in[2];
  const int*   chain  = (const int*)d_in[3];
  const float* w_pos  = (const float*)d_in[4];
  const float* b_pos  = (const float*)d_in[5];
  const float* w_edge = (const float*)d_in[6];
  const float* gamma  = (const float*)d_in[7];
  const float* beta   = (const float*)d_in[8];

  float* outE = (float*)d_out;                         // output 0: E, float32
  float* outI = outE + (size_t)BB * NRES * TOPK * NCH; // output 1: E_idx as float32

  // workspace layout
  char* p = (char*)d_ws;
  float* atoms = (float*)p;                 p += (size_t)BB * NRES * 16 * 4;   // 256 KB
  int*   eidx  = (int*)p;                   p += (size_t)BB * NRES * TOPK * 4; // 480 KB
  float* dn    = (float*)p;                 p += (size_t)BB * NRES * TOPK * 4; // 480 KB
  unsigned* wB8 = (unsigned*)p;             p += (size_t)NCH * NFEAT;          // 52 KB
  float4* Cpk  = (float4*)p;                // 64 KB

  prep_kernel<<<16 + (NFEAT * NCH / 4 + 255) / 256, 256, 0, stream>>>(X, w_edge, atoms, Cpk, wB8);
  topk_kernel<<<BB * NRES / 4, 256, 0, stream>>>(Cpk, eidx, dn, outI);
  edge_mfma_kernel<<<BB * NRES, 256, 0, stream>>>(atoms, eidx, dn, ridx, chain,
                                                  w_pos, b_pos, wB8, gamma, beta, outE);
}